// Round 3
// baseline (435.085 us; speedup 1.0000x reference)
//
#include <hip/hip_runtime.h>
#include <stdint.h>

// ---------------------------------------------------------------------------
// LSH layer: out[n,s] = sum_d x[n,d] * W[ids[s],d] + bias[ids[s]]
// R3: GEMM switched from 4x4 of 16x16x32 MFMA to 2x2 of 32x32x16 MFMA per
//     wave (same 64x64 wave tile). Same LDS bytes, half the MFMA instrs,
//     -17% matrix-pipe cycles (8.07 vs 2*4.85 cyc per 32k FLOP), wider
//     (128 B/half-wave) epilogue store segments. XOR chunk swizzle kept.
//     Added bn-group block swizzle for L2 reuse of W tiles.
// ---------------------------------------------------------------------------

typedef __bf16 bf16x8 __attribute__((ext_vector_type(8)));
typedef float f32x16 __attribute__((ext_vector_type(16)));

#define BM 128
#define BN 128
#define BK 64

__device__ __forceinline__ ushort f2bf(float f) {
  union { float f; uint32_t u; } c; c.f = f;
  uint32_t u = c.u;
  return (ushort)((u + 0x7FFFu + ((u >> 16) & 1u)) >> 16);
}

// blocks [0, S/8): gather 8 W rows -> bf16 + bias gather
// blocks [S/8, ...): convert x -> bf16
__global__ __launch_bounds__(256) void prep_kernel(
    const float* __restrict__ x, const float* __restrict__ W,
    const float* __restrict__ bias, const int* __restrict__ ids,
    ushort* __restrict__ Wg, ushort* __restrict__ xb,
    float* __restrict__ biasg, int D, int S) {
  const int t = threadIdx.x;
  const int gblocks = S >> 3;
  if ((int)blockIdx.x < gblocks) {
    const int s0 = blockIdx.x << 3;
    if (t < 8) biasg[s0 + t] = bias[ids[s0 + t]];
#pragma unroll
    for (int r = 0; r < 8; ++r) {
      const int s = s0 + r;
      const int id = ids[s];
      float4 v = ((const float4*)(W + (size_t)id * D))[t];
      ushort4 o;
      o.x = f2bf(v.x); o.y = f2bf(v.y); o.z = f2bf(v.z); o.w = f2bf(v.w);
      ((ushort4*)(Wg + (size_t)s * D))[t] = o;
    }
  } else {
    const int i = (blockIdx.x - gblocks) * 256 + t;
    float4 v = ((const float4*)x)[i];
    ushort4 o;
    o.x = f2bf(v.x); o.y = f2bf(v.y); o.z = f2bf(v.z); o.w = f2bf(v.w);
    ((ushort4*)xb)[i] = o;
  }
}

__device__ __forceinline__ void load_lds16(const void* g, void* l) {
  __builtin_amdgcn_global_load_lds(
      (const __attribute__((address_space(1))) void*)g,
      (__attribute__((address_space(3))) void*)l, 16, 0, 0);
}

// Swizzled LDS addressing: physical chunk p at row r holds logical chunk
// c = p ^ (r & 7). One chunk = 8 ushorts = 16 B. Row = BK = 8 chunks.
__device__ __forceinline__ const ushort* frag_ptr(const ushort* base, int row,
                                                  int c) {
  return base + row * BK + (((c ^ (row & 7)) << 3));
}

// C[M,S] = A[M,K](bf16) * B[S,K](bf16)^T + biasg[S], fp32 out.
// 256 thr = 4 waves (2x2 of 64x64), each wave 2x2 of 32x32x16 MFMA tiles.
__global__ __launch_bounds__(256) void gemm_bt_bias(
    const ushort* __restrict__ A, const ushort* __restrict__ B,
    const float* __restrict__ biasg, float* __restrict__ C,
    int M, int S, int K) {
  __shared__ __align__(16) ushort As[BM * BK];
  __shared__ __align__(16) ushort Bs[BN * BK];

  const int tid  = threadIdx.x;
  const int lane = tid & 63;
  const int wave = tid >> 6;

  // block swizzle: groups of 8 bn-columns, bm-major inside the group ->
  // a group's working set is 8 W-tiles (2 MB) x 16 x-tiles (4 MB), L2-sized.
  const int num_bm = M / BM;                 // 16
  const int pid = blockIdx.x;
  const int group_sz = num_bm * 8;
  const int g = pid / group_sz;
  const int r = pid % group_sz;
  const int bn = g * 8 + (r & 7);
  const int bm = r >> 3;

  const int wm = (wave >> 1) * 64;
  const int wn = (wave & 1) * 64;
  const int l31  = lane & 31;
  const int half = lane >> 5;

  // staging: thread tid -> LDS slot tid*16B == (row=tid/8, phys chunk=tid%8).
  // phys chunk p holds logical chunk p ^ (row&7)  ->  global col = that chunk.
  const int srow = tid >> 3;
  const int scol = (((tid & 7) ^ (srow & 7)) << 3);
  const ushort* Ag = A + (size_t)(bm * BM + srow) * K + scol;
  const ushort* Bg = B + (size_t)(bn * BN + srow) * K + scol;
  ushort* Asl = As + tid * 8;   // wave-uniform base + lane*16B
  ushort* Bsl = Bs + tid * 8;

  f32x16 acc[2][2] = {};

  for (int kt = 0; kt < K; kt += BK) {
#pragma unroll
    for (int i = 0; i < 4; ++i) {
      load_lds16(Ag + (size_t)(i * 32) * K, Asl + i * 32 * BK);
      load_lds16(Bg + (size_t)(i * 32) * K, Bsl + i * 32 * BK);
    }
    Ag += BK; Bg += BK;
    __syncthreads();

#pragma unroll
    for (int ks = 0; ks < BK; ks += 16) {
      // A-frag layout for 32x32x16: m = lane&31, k = (lane>>5)*8 + j
      const int c0 = (ks >> 3) + half;  // logical 16B chunk for this frag
      bf16x8 af[2], bq[2];
#pragma unroll
      for (int i = 0; i < 2; ++i)
        af[i] = *(const bf16x8*)frag_ptr(As, wm + i * 32 + l31, c0);
#pragma unroll
      for (int j = 0; j < 2; ++j)
        bq[j] = *(const bf16x8*)frag_ptr(Bs, wn + j * 32 + l31, c0);
#pragma unroll
      for (int i = 0; i < 2; ++i)
#pragma unroll
        for (int j = 0; j < 2; ++j)
          acc[i][j] = __builtin_amdgcn_mfma_f32_32x32x16_bf16(
              af[i], bq[j], acc[i][j], 0, 0, 0);
    }
    __syncthreads();
  }

  // epilogue: C/D 32x32 layout: col = lane&31,
  // row = (reg&3) + 8*(reg>>2) + 4*(lane>>5)   [m74/m101 verified]
  const int row_base = bm * BM + wm + 4 * half;
  const int col_base = bn * BN + wn + l31;
#pragma unroll
  for (int j = 0; j < 2; ++j) {
    const int col = col_base + j * 32;
    const float bv = biasg[col];
#pragma unroll
    for (int i = 0; i < 2; ++i) {
#pragma unroll
      for (int reg = 0; reg < 16; ++reg) {
        const int row = row_base + i * 32 + (reg & 3) + 8 * (reg >> 2);
        C[(size_t)row * S + col] = acc[i][j][reg] + bv;
      }
    }
  }
}

extern "C" void kernel_launch(void* const* d_in, const int* in_sizes, int n_in,
                              void* d_out, int out_size, void* d_ws, size_t ws_size,
                              hipStream_t stream) {
  const float* x    = (const float*)d_in[0];  // [N, D]
  const float* W    = (const float*)d_in[1];  // [OUT, D]
  const float* bias = (const float*)d_in[2];  // [OUT]
  const int*   ids  = (const int*)d_in[3];    // [S]
  float* out = (float*)d_out;                 // [N, S]

  const int OUTN = in_sizes[2];
  const int S    = in_sizes[3];
  const int D    = in_sizes[1] / OUTN;  // 1024
  const int N    = in_sizes[0] / D;     // 2048

  // workspace: Wg bf16 [S,D] | xb bf16 [N,D] | biasg f32 [S]
  ushort* Wg = (ushort*)d_ws;
  ushort* xb = (ushort*)((char*)d_ws + (size_t)S * D * sizeof(ushort));
  float* biasg = (float*)((char*)d_ws + (size_t)S * D * sizeof(ushort)
                          + (size_t)N * D * sizeof(ushort));

  const int gather_blocks = S / 8;
  const int conv_blocks = (N * D) / 1024;  // 256 thr * 4 floats
  prep_kernel<<<gather_blocks + conv_blocks, 256, 0, stream>>>(
      x, W, bias, ids, Wg, xb, biasg, D, S);

  const int total_blocks = (S / BN) * (N / BM);
  gemm_bt_bias<<<total_blocks, 256, 0, stream>>>(xb, Wg, biasg, out, N, S, D);
}